// Round 5
// baseline (636.022 us; speedup 1.0000x reference)
//
#include <hip/hip_runtime.h>
#include <hip/hip_bf16.h>

#define NNODE 10000
#define NEDGE 160000
#define HIDD  256
#define ED    128
#define CAT   640

typedef short bf8 __attribute__((ext_vector_type(8)));
typedef float f4  __attribute__((ext_vector_type(4)));
typedef unsigned int u32;

__device__ __forceinline__ float bf2f(ushort u) {
    return __uint_as_float(((unsigned)u) << 16);
}
__device__ __forceinline__ ushort f2bf(float f) {
    unsigned u = __float_as_uint(f);
    return (ushort)((u + 0x7fffu + ((u >> 16) & 1u)) >> 16);
}
__device__ __forceinline__ float gelu_exact(float x) {
    return 0.5f * x * (1.0f + erff(x * 0.70710678118654752f));
}
__device__ __forceinline__ int clampi(int v) {
    return ((unsigned)v >= (unsigned)NNODE) ? 0 : v;
}
__device__ __forceinline__ int getidx(const int* ei, bool i64, int pos) {
    int v = i64 ? ei[2 * pos] : ei[pos];
    return clampi(v);
}
__device__ __forceinline__ float loadf(const void* p, size_t idx, bool f32) {
    return f32 ? ((const float*)p)[idx] : bf2f(((const ushort*)p)[idx]);
}
__device__ __forceinline__ bf8 load8(const void* p, size_t idx, bool f32) {
    if (f32) {
        const float* fp = (const float*)p + idx;
        f4 lo = *(const f4*)fp, hi = *(const f4*)(fp + 4);
        bf8 r;
        r[0] = (short)f2bf(lo[0]); r[1] = (short)f2bf(lo[1]);
        r[2] = (short)f2bf(lo[2]); r[3] = (short)f2bf(lo[3]);
        r[4] = (short)f2bf(hi[0]); r[5] = (short)f2bf(hi[1]);
        r[6] = (short)f2bf(hi[2]); r[7] = (short)f2bf(hi[3]);
        return r;
    }
    return *(const bf8*)((const ushort*)p + idx);
}
__device__ __forceinline__ void storef(void* p, size_t idx, float v, bool f32) {
    if (f32) ((float*)p)[idx] = v;
    else     ((ushort*)p)[idx] = f2bf(v);
}

// ---- runtime dtype detection ----
__global__ void detect_kernel(const u32* __restrict__ h_u32,
                              const u32* __restrict__ ei_u32,
                              u32* __restrict__ flags) {
    if (threadIdx.x == 0 && blockIdx.x == 0) {
        int inwin = 0;
        for (int i = 0; i < 64; ++i) {
            u32 e8 = (h_u32[i] >> 7) & 0xFFu;
            if (e8 >= 100u && e8 <= 150u) ++inwin;
        }
        u32 f32 = (inwin < 40) ? 1u : 0u;
        u32 hi_or = 0;
        for (int j = 0; j < 16; ++j) hi_or |= ei_u32[2 * j + 1];
        u32 i64 = (hi_or == 0u) ? 1u : 0u;
        flags[0] = f32;
        flags[1] = i64;
    }
}

// ---- weight transpose to bf16 n-major: WT[n][k] = bf16(W[k][n]) ----
__global__ void wt_kernel(const void* __restrict__ W, ushort* __restrict__ WT,
                          int K, int N, const u32* __restrict__ flags) {
    const bool f32 = flags[0] != 0;
    int k = blockIdx.x, n = threadIdx.x;
    if (k < K && n < N)
        WT[(size_t)n * K + k] = f2bf(loadf(W, (size_t)k * N + n, f32));
}

// ---- h convert to bf16 ----
__global__ void hconv_kernel(const void* __restrict__ h, ushort* __restrict__ hb,
                             const u32* __restrict__ flags) {
    const bool f32 = flags[0] != 0;
    int i = blockIdx.x * 256 + threadIdx.x;
    if (i < NNODE * HIDD / 8)
        *(bf8*)&hb[(size_t)i * 8] = load8(h, (size_t)i * 8, f32);
}

// ---- per-dst edge counts ----
__global__ void count_kernel(const int* __restrict__ ei, u32* __restrict__ cnt,
                             const u32* __restrict__ flags) {
    bool i64 = flags[1] != 0;
    int i = blockIdx.x * 256 + threadIdx.x;
    if (i < NEDGE) atomicAdd(&cnt[getidx(ei, i64, NEDGE + i)], 1u);
}

// ---- edge update: e_new = LN(e + MLP([h_src|h_dst|e])) ----
// 64 edges/block, 4 waves, each wave owns a 32-col slice of N=128.
// A and B fragments read DIRECTLY from global (L2); LDS only for T1 + LN exchange.
__global__ __launch_bounds__(256) void edge_kernel(
    const ushort* __restrict__ hb, const void* __restrict__ e,
    const int* __restrict__ ei,
    const ushort* __restrict__ WT1, const void* __restrict__ be1,
    const ushort* __restrict__ WT2, const void* __restrict__ be2,
    const void* __restrict__ neg, const void* __restrict__ neb,
    void* __restrict__ out, const u32* __restrict__ flags)
{
    const bool f32 = flags[0] != 0, i64 = flags[1] != 0;
    constexpr int LDT = 136, LDV = 132;
    __shared__ ushort Tsm[64 * LDT];   // T1 bf16 [64 rows][128]
    __shared__ float  Vsm[64 * LDV];   // phase-2 f32 result for LN

    const int tid = threadIdx.x;
    const int wid = tid >> 6, lane = tid & 63;
    const int l16 = lane & 15, lg = lane >> 4;
    const int edge0 = blockIdx.x * 64;
    const int n0 = wid * 32;

    // per-lane A row bases
    size_t hs[4], hd[4], er[4];
    #pragma unroll
    for (int ai = 0; ai < 4; ++ai) {
        int row = edge0 + ai * 16 + l16;
        hs[ai] = (size_t)getidx(ei, i64, row) * HIDD;
        hd[ai] = (size_t)getidx(ei, i64, NEDGE + row) * HIDD;
        er[ai] = (size_t)row * ED;
    }
    int bb1[2], bb2[2];
    #pragma unroll
    for (int bi = 0; bi < 2; ++bi) {
        bb1[bi] = (n0 + bi * 16 + l16) * CAT;
        bb2[bi] = (n0 + bi * 16 + l16) * ED;
    }

    f4 acc[4][2] = {};
    // phase 1: K=640 split [h_src 0:256 | h_dst 256:512 | e 512:640]
    for (int kc = 0; kc < 8; ++kc) {
        #pragma unroll
        for (int ks = 0; ks < 2; ++ks) {
            int kk = kc * 32 + ks * 16 + lg * 8;   // 0..255
            bf8 b0 = *(const bf8*)&WT1[bb1[0] + (kc < 4 ? 0 : 256) + (kc & 3) * 64 + ks * 32 + lg * 8];
            (void)b0;
        }
        break; // placeholder removed below
    }
    // (real loops)
    {
        // h_src segment: k = 0..255
        for (int kc = 0; kc < 4; ++kc) {
            #pragma unroll
            for (int ks = 0; ks < 2; ++ks) {
                int kk = kc * 64 + ks * 32 + lg * 8;
                bf8 b0 = *(const bf8*)&WT1[bb1[0] + kk];
                bf8 b1 = *(const bf8*)&WT1[bb1[1] + kk];
                #pragma unroll
                for (int ai = 0; ai < 4; ++ai) {
                    bf8 a = *(const bf8*)&hb[hs[ai] + kk];
                    acc[ai][0] = __builtin_amdgcn_mfma_f32_16x16x32_bf16(a, b0, acc[ai][0], 0, 0, 0);
                    acc[ai][1] = __builtin_amdgcn_mfma_f32_16x16x32_bf16(a, b1, acc[ai][1], 0, 0, 0);
                }
            }
        }
        // h_dst segment: k = 256..511
        for (int kc = 0; kc < 4; ++kc) {
            #pragma unroll
            for (int ks = 0; ks < 2; ++ks) {
                int kk = kc * 64 + ks * 32 + lg * 8;
                bf8 b0 = *(const bf8*)&WT1[bb1[0] + 256 + kk];
                bf8 b1 = *(const bf8*)&WT1[bb1[1] + 256 + kk];
                #pragma unroll
                for (int ai = 0; ai < 4; ++ai) {
                    bf8 a = *(const bf8*)&hb[hd[ai] + kk];
                    acc[ai][0] = __builtin_amdgcn_mfma_f32_16x16x32_bf16(a, b0, acc[ai][0], 0, 0, 0);
                    acc[ai][1] = __builtin_amdgcn_mfma_f32_16x16x32_bf16(a, b1, acc[ai][1], 0, 0, 0);
                }
            }
        }
        // e segment: k = 512..639
        for (int kc = 0; kc < 2; ++kc) {
            #pragma unroll
            for (int ks = 0; ks < 2; ++ks) {
                int kk = kc * 64 + ks * 32 + lg * 8;
                bf8 b0 = *(const bf8*)&WT1[bb1[0] + 512 + kk];
                bf8 b1 = *(const bf8*)&WT1[bb1[1] + 512 + kk];
                #pragma unroll
                for (int ai = 0; ai < 4; ++ai) {
                    bf8 a = load8(e, er[ai] + kk, f32);
                    acc[ai][0] = __builtin_amdgcn_mfma_f32_16x16x32_bf16(a, b0, acc[ai][0], 0, 0, 0);
                    acc[ai][1] = __builtin_amdgcn_mfma_f32_16x16x32_bf16(a, b1, acc[ai][1], 0, 0, 0);
                }
            }
        }
    }

    // epilogue 1: bias + gelu -> Tsm
    #pragma unroll
    for (int bi = 0; bi < 2; ++bi) {
        int col = n0 + bi * 16 + l16;
        float bias = loadf(be1, col, f32);
        #pragma unroll
        for (int ai = 0; ai < 4; ++ai)
            #pragma unroll
            for (int r = 0; r < 4; ++r)
                Tsm[(ai * 16 + lg * 4 + r) * LDT + col] = f2bf(gelu_exact(acc[ai][bi][r] + bias));
    }
    __syncthreads();

    // phase 2: T2 = T1 @ We2, K=128; A from Tsm, B direct from WT2
    f4 acc2[4][2] = {};
    for (int kc = 0; kc < 2; ++kc) {
        #pragma unroll
        for (int ks = 0; ks < 2; ++ks) {
            int kk = kc * 64 + ks * 32 + lg * 8;
            bf8 b0 = *(const bf8*)&WT2[bb2[0] + kk];
            bf8 b1 = *(const bf8*)&WT2[bb2[1] + kk];
            #pragma unroll
            for (int ai = 0; ai < 4; ++ai) {
                bf8 a = *(const bf8*)&Tsm[(ai * 16 + l16) * LDT + kk];
                acc2[ai][0] = __builtin_amdgcn_mfma_f32_16x16x32_bf16(a, b0, acc2[ai][0], 0, 0, 0);
                acc2[ai][1] = __builtin_amdgcn_mfma_f32_16x16x32_bf16(a, b1, acc2[ai][1], 0, 0, 0);
            }
        }
    }

    // epilogue 2: + bias + residual e -> Vsm (f32)
    #pragma unroll
    for (int bi = 0; bi < 2; ++bi) {
        int col = n0 + bi * 16 + l16;
        float bias = loadf(be2, col, f32);
        #pragma unroll
        for (int ai = 0; ai < 4; ++ai)
            #pragma unroll
            for (int r = 0; r < 4; ++r) {
                int row = ai * 16 + lg * 4 + r;
                Vsm[row * LDV + col] = acc2[ai][bi][r] + bias
                                     + loadf(e, (size_t)(edge0 + row) * ED + col, f32);
            }
    }
    __syncthreads();

    // LN over 128 cols; wave wid handles rows wid*16..+15
    #pragma unroll
    for (int rr = 0; rr < 4; ++rr) {
        int row = wid * 16 + lg * 4 + rr;
        float x[8];
        #pragma unroll
        for (int f = 0; f < 8; ++f) x[f] = Vsm[row * LDV + f * 16 + l16];
        float s = 0.f;
        #pragma unroll
        for (int f = 0; f < 8; ++f) s += x[f];
        s += __shfl_xor(s, 1); s += __shfl_xor(s, 2);
        s += __shfl_xor(s, 4); s += __shfl_xor(s, 8);
        float mu = s * (1.0f / 128.0f);
        float q = 0.f;
        #pragma unroll
        for (int f = 0; f < 8; ++f) { float d = x[f] - mu; q += d * d; }
        q += __shfl_xor(q, 1); q += __shfl_xor(q, 2);
        q += __shfl_xor(q, 4); q += __shfl_xor(q, 8);
        float rstd = rsqrtf(q * (1.0f / 128.0f) + 1e-5f);
        #pragma unroll
        for (int f = 0; f < 8; ++f) {
            int col = f * 16 + l16;
            float y = (x[f] - mu) * rstd * loadf(neg, col, f32) + loadf(neb, col, f32);
            storef(out, (size_t)NNODE * HIDD + (size_t)(edge0 + row) * ED + col, y, f32);
        }
    }
}

// ---- node phase 1: S[dst] += gelu([h_src|h_dst|e_new] @ Wv1 + bv1) ----
// Barrier-free, no LDS. 64 edges/block, each wave owns 64-col slice of N=256.
__global__ __launch_bounds__(256) void node1_kernel(
    const ushort* __restrict__ hb, const void* __restrict__ out /*e_new*/,
    const int* __restrict__ ei,
    const ushort* __restrict__ WTv1, const void* __restrict__ bv1,
    float* __restrict__ S, const u32* __restrict__ flags)
{
    const bool f32 = flags[0] != 0, i64 = flags[1] != 0;
    const int tid = threadIdx.x;
    const int wid = tid >> 6, lane = tid & 63;
    const int l16 = lane & 15, lg = lane >> 4;
    const int edge0 = blockIdx.x * 64;
    const int n0 = wid * 64;
    const size_t EOFF = (size_t)NNODE * HIDD;

    size_t hs[4], hd[4], er[4];
    #pragma unroll
    for (int ai = 0; ai < 4; ++ai) {
        int row = edge0 + ai * 16 + l16;
        hs[ai] = (size_t)getidx(ei, i64, row) * HIDD;
        hd[ai] = (size_t)getidx(ei, i64, NEDGE + row) * HIDD;
        er[ai] = EOFF + (size_t)row * ED;
    }
    int bb[4];
    #pragma unroll
    for (int bi = 0; bi < 4; ++bi) bb[bi] = (n0 + bi * 16 + l16) * CAT;

    f4 acc[4][4] = {};
    // h_src
    for (int kc = 0; kc < 4; ++kc) {
        #pragma unroll
        for (int ks = 0; ks < 2; ++ks) {
            int kk = kc * 64 + ks * 32 + lg * 8;
            bf8 b[4];
            #pragma unroll
            for (int bi = 0; bi < 4; ++bi) b[bi] = *(const bf8*)&WTv1[bb[bi] + kk];
            #pragma unroll
            for (int ai = 0; ai < 4; ++ai) {
                bf8 a = *(const bf8*)&hb[hs[ai] + kk];
                #pragma unroll
                for (int bi = 0; bi < 4; ++bi)
                    acc[ai][bi] = __builtin_amdgcn_mfma_f32_16x16x32_bf16(a, b[bi], acc[ai][bi], 0, 0, 0);
            }
        }
    }
    // h_dst
    for (int kc = 0; kc < 4; ++kc) {
        #pragma unroll
        for (int ks = 0; ks < 2; ++ks) {
            int kk = kc * 64 + ks * 32 + lg * 8;
            bf8 b[4];
            #pragma unroll
            for (int bi = 0; bi < 4; ++bi) b[bi] = *(const bf8*)&WTv1[bb[bi] + 256 + kk];
            #pragma unroll
            for (int ai = 0; ai < 4; ++ai) {
                bf8 a = *(const bf8*)&hb[hd[ai] + kk];
                #pragma unroll
                for (int bi = 0; bi < 4; ++bi)
                    acc[ai][bi] = __builtin_amdgcn_mfma_f32_16x16x32_bf16(a, b[bi], acc[ai][bi], 0, 0, 0);
            }
        }
    }
    // e_new
    for (int kc = 0; kc < 2; ++kc) {
        #pragma unroll
        for (int ks = 0; ks < 2; ++ks) {
            int kk = kc * 64 + ks * 32 + lg * 8;
            bf8 b[4];
            #pragma unroll
            for (int bi = 0; bi < 4; ++bi) b[bi] = *(const bf8*)&WTv1[bb[bi] + 512 + kk];
            #pragma unroll
            for (int ai = 0; ai < 4; ++ai) {
                bf8 a = load8(out, er[ai] + kk, f32);
                #pragma unroll
                for (int bi = 0; bi < 4; ++bi)
                    acc[ai][bi] = __builtin_amdgcn_mfma_f32_16x16x32_bf16(a, b[bi], acc[ai][bi], 0, 0, 0);
            }
        }
    }

    // gelu + scatter into S
    float bias[4];
    #pragma unroll
    for (int bi = 0; bi < 4; ++bi) bias[bi] = loadf(bv1, n0 + bi * 16 + l16, f32);
    #pragma unroll
    for (int ai = 0; ai < 4; ++ai) {
        #pragma unroll
        for (int r = 0; r < 4; ++r) {
            int erow = edge0 + ai * 16 + lg * 4 + r;
            int dst = getidx(ei, i64, NEDGE + erow);
            float* sp = S + (size_t)dst * HIDD;
            #pragma unroll
            for (int bi = 0; bi < 4; ++bi)
                atomicAdd(&sp[n0 + bi * 16 + l16], gelu_exact(acc[ai][bi][r] + bias[bi]));
        }
    }
}

// ---- node phase 2 + LN: h_new = LN(h + (S@Wv2 + cnt*bv2)/max(cnt,1)) ----
__global__ __launch_bounds__(256) void hn_gemm_kernel(
    const float* __restrict__ S, const ushort* __restrict__ WTv2,
    const void* __restrict__ bv2, const u32* __restrict__ cnt,
    const void* __restrict__ h,
    const void* __restrict__ nvg, const void* __restrict__ nvb,
    void* __restrict__ out, const u32* __restrict__ flags)
{
    const bool f32 = flags[0] != 0;
    constexpr int LDV = 260;
    __shared__ float Vsm[64 * LDV];

    const int tid = threadIdx.x;
    const int wid = tid >> 6, lane = tid & 63;
    const int l16 = lane & 15, lg = lane >> 4;
    const int node0 = blockIdx.x * 64;
    const int n0 = wid * 64;

    size_t ra[4];
    #pragma unroll
    for (int ai = 0; ai < 4; ++ai) {
        int row = node0 + ai * 16 + l16;
        ra[ai] = (size_t)(row < NNODE ? row : NNODE - 1) * HIDD;
    }
    int bb[4];
    #pragma unroll
    for (int bi = 0; bi < 4; ++bi) bb[bi] = (n0 + bi * 16 + l16) * HIDD;

    f4 acc[4][4] = {};
    for (int kc = 0; kc < 4; ++kc) {
        #pragma unroll
        for (int ks = 0; ks < 2; ++ks) {
            int kk = kc * 64 + ks * 32 + lg * 8;
            bf8 b[4];
            #pragma unroll
            for (int bi = 0; bi < 4; ++bi) b[bi] = *(const bf8*)&WTv2[bb[bi] + kk];
            #pragma unroll
            for (int ai = 0; ai < 4; ++ai) {
                bf8 a = load8(S, ra[ai] + kk, true);   // S is always f32
                #pragma unroll
                for (int bi = 0; bi < 4; ++bi)
                    acc[ai][bi] = __builtin_amdgcn_mfma_f32_16x16x32_bf16(a, b[bi], acc[ai][bi], 0, 0, 0);
            }
        }
    }

    // epilogue: mean + bias + residual -> Vsm
    #pragma unroll
    for (int bi = 0; bi < 4; ++bi) {
        int col = n0 + bi * 16 + l16;
        float b2 = loadf(bv2, col, f32);
        #pragma unroll
        for (int ai = 0; ai < 4; ++ai)
            #pragma unroll
            for (int r = 0; r < 4; ++r) {
                int rowl = ai * 16 + lg * 4 + r;
                int gr = node0 + rowl;
                int grc = gr < NNODE ? gr : NNODE - 1;
                float c = (float)cnt[grc];
                float inv = 1.0f / fmaxf(c, 1.0f);
                float val = (acc[ai][bi][r] + c * b2) * inv
                          + loadf(h, (size_t)grc * HIDD + col, f32);
                Vsm[rowl * LDV + col] = val;
            }
    }
    __syncthreads();

    // LN over 256 cols; wave wid handles rows wid*16..+15
    #pragma unroll
    for (int rr = 0; rr < 4; ++rr) {
        int rowl = wid * 16 + lg * 4 + rr;
        int gr = node0 + rowl;
        float x[16];
        #pragma unroll
        for (int f = 0; f < 16; ++f) x[f] = Vsm[rowl * LDV + f * 16 + l16];
        float s = 0.f;
        #pragma unroll
        for (int f = 0; f < 16; ++f) s += x[f];
        s += __shfl_xor(s, 1); s += __shfl_xor(s, 2);
        s += __shfl_xor(s, 4); s += __shfl_xor(s, 8);
        float mu = s * (1.0f / 256.0f);
        float q = 0.f;
        #pragma unroll
        for (int f = 0; f < 16; ++f) { float d = x[f] - mu; q += d * d; }
        q += __shfl_xor(q, 1); q += __shfl_xor(q, 2);
        q += __shfl_xor(q, 4); q += __shfl_xor(q, 8);
        float rstd = rsqrtf(q * (1.0f / 256.0f) + 1e-5f);
        if (gr < NNODE) {
            #pragma unroll
            for (int f = 0; f < 16; ++f) {
                int col = f * 16 + l16;
                float y = (x[f] - mu) * rstd * loadf(nvg, col, f32) + loadf(nvb, col, f32);
                storef(out, (size_t)gr * HIDD + col, y, f32);
            }
        }
    }
}

extern "C" void kernel_launch(void* const* d_in, const int* in_sizes, int n_in,
                              void* d_out, int out_size, void* d_ws, size_t ws_size,
                              hipStream_t stream)
{
    (void)in_sizes; (void)n_in; (void)out_size; (void)ws_size;
    const void* h   = d_in[0];
    const void* e   = d_in[1];
    const int*  ei  = (const int*)d_in[2];
    const void* We1 = d_in[3];
    const void* be1 = d_in[4];
    const void* We2 = d_in[5];
    const void* be2 = d_in[6];
    const void* Wv1 = d_in[7];
    const void* bv1 = d_in[8];
    const void* Wv2 = d_in[9];
    const void* bv2 = d_in[10];
    const void* neg = d_in[11];
    const void* neb = d_in[12];
    const void* nvg = d_in[13];
    const void* nvb = d_in[14];

    char* ws = (char*)d_ws;
    u32*   flags = (u32*)ws;                                    // 256B slot
    float* S     = (float*)(ws + 256);                          // 10.24 MB
    u32*   cnt   = (u32*)(ws + 256 + (size_t)NNODE * HIDD * 4); // 40 KB
    size_t off = 256 + (size_t)NNODE * HIDD * 4 + ((size_t)NNODE * 4 + 255) / 256 * 256;
    ushort* WT1  = (ushort*)(ws + off);            // [128][640]
    ushort* WT2  = WT1 + (size_t)ED * CAT;         // [128][128]
    ushort* WTv1 = WT2 + (size_t)ED * ED;          // [256][640]
    ushort* WTv2 = WTv1 + (size_t)HIDD * CAT;      // [256][256]
    ushort* hb   = WTv2 + (size_t)HIDD * HIDD;     // [10000][256] bf16

    hipMemsetAsync(S, 0, (size_t)NNODE * HIDD * 4 + (size_t)NNODE * 4, stream);
    detect_kernel<<<1, 64, 0, stream>>>((const u32*)h, (const u32*)ei, flags);

    wt_kernel<<<CAT,  ED,   0, stream>>>(We1, WT1, CAT, ED, flags);
    wt_kernel<<<ED,   ED,   0, stream>>>(We2, WT2, ED, ED, flags);
    wt_kernel<<<CAT,  HIDD, 0, stream>>>(Wv1, WTv1, CAT, HIDD, flags);
    wt_kernel<<<HIDD, HIDD, 0, stream>>>(Wv2, WTv2, HIDD, HIDD, flags);
    hconv_kernel<<<(NNODE * HIDD / 8 + 255) / 256, 256, 0, stream>>>(h, hb, flags);
    count_kernel<<<(NEDGE + 255) / 256, 256, 0, stream>>>(ei, cnt, flags);

    edge_kernel<<<NEDGE / 64, 256, 0, stream>>>(hb, e, ei, WT1, be1, WT2, be2,
                                                neg, neb, d_out, flags);
    node1_kernel<<<NEDGE / 64, 256, 0, stream>>>(hb, d_out, ei, WTv1, bv1, S, flags);
    hn_gemm_kernel<<<(NNODE + 63) / 64, 256, 0, stream>>>(S, WTv2, bv2, cnt, h,
                                                          nvg, nvb, d_out, flags);
}

// Round 6
// 412.981 us; speedup vs baseline: 1.5401x; 1.5401x over previous
//
#include <hip/hip_runtime.h>
#include <hip/hip_bf16.h>

#define NNODE 10000
#define NEDGE 160000
#define HIDD  256
#define ED    128
#define CAT   640

typedef short bf8 __attribute__((ext_vector_type(8)));
typedef float f4  __attribute__((ext_vector_type(4)));
typedef unsigned int u32;

__device__ __forceinline__ float bf2f(ushort u) {
    return __uint_as_float(((unsigned)u) << 16);
}
__device__ __forceinline__ ushort f2bf(float f) {
    unsigned u = __float_as_uint(f);
    return (ushort)((u + 0x7fffu + ((u >> 16) & 1u)) >> 16);
}
__device__ __forceinline__ float gelu_exact(float x) {
    return 0.5f * x * (1.0f + erff(x * 0.70710678118654752f));
}
__device__ __forceinline__ int clampi(int v) {
    return ((unsigned)v >= (unsigned)NNODE) ? 0 : v;
}
__device__ __forceinline__ int getidx(const int* ei, bool i64, int pos) {
    int v = i64 ? ei[2 * pos] : ei[pos];
    return clampi(v);
}
__device__ __forceinline__ float loadf(const void* p, size_t idx, bool f32) {
    return f32 ? ((const float*)p)[idx] : bf2f(((const ushort*)p)[idx]);
}
__device__ __forceinline__ bf8 load8(const void* p, size_t idx, bool f32) {
    if (f32) {
        const float* fp = (const float*)p + idx;
        f4 lo = *(const f4*)fp, hi = *(const f4*)(fp + 4);
        bf8 r;
        r[0] = (short)f2bf(lo[0]); r[1] = (short)f2bf(lo[1]);
        r[2] = (short)f2bf(lo[2]); r[3] = (short)f2bf(lo[3]);
        r[4] = (short)f2bf(hi[0]); r[5] = (short)f2bf(hi[1]);
        r[6] = (short)f2bf(hi[2]); r[7] = (short)f2bf(hi[3]);
        return r;
    }
    return *(const bf8*)((const ushort*)p + idx);
}
__device__ __forceinline__ void storef(void* p, size_t idx, float v, bool f32) {
    if (f32) ((float*)p)[idx] = v;
    else     ((ushort*)p)[idx] = f2bf(v);
}

// ---- runtime dtype detection ----
__global__ void detect_kernel(const u32* __restrict__ h_u32,
                              const u32* __restrict__ ei_u32,
                              u32* __restrict__ flags) {
    if (threadIdx.x == 0 && blockIdx.x == 0) {
        int inwin = 0;
        for (int i = 0; i < 64; ++i) {
            u32 e8 = (h_u32[i] >> 7) & 0xFFu;
            if (e8 >= 100u && e8 <= 150u) ++inwin;
        }
        u32 f32 = (inwin < 40) ? 1u : 0u;
        u32 hi_or = 0;
        for (int j = 0; j < 16; ++j) hi_or |= ei_u32[2 * j + 1];
        u32 i64 = (hi_or == 0u) ? 1u : 0u;
        flags[0] = f32;
        flags[1] = i64;
    }
}

// ---- weight transpose to bf16 n-major: WT[n][k] = bf16(W[k][n]) ----
__global__ void wt_kernel(const void* __restrict__ W, ushort* __restrict__ WT,
                          int K, int N, const u32* __restrict__ flags) {
    const bool f32 = flags[0] != 0;
    int k = blockIdx.x, n = threadIdx.x;
    if (k < K && n < N)
        WT[(size_t)n * K + k] = f2bf(loadf(W, (size_t)k * N + n, f32));
}

// ---- h convert to bf16 ----
__global__ void hconv_kernel(const void* __restrict__ h, ushort* __restrict__ hb,
                             const u32* __restrict__ flags) {
    const bool f32 = flags[0] != 0;
    int i = blockIdx.x * 256 + threadIdx.x;
    if (i < NNODE * HIDD / 8)
        *(bf8*)&hb[(size_t)i * 8] = load8(h, (size_t)i * 8, f32);
}

// ---- per-dst edge counts ----
__global__ void count_kernel(const int* __restrict__ ei, u32* __restrict__ cnt,
                             const u32* __restrict__ flags) {
    bool i64 = flags[1] != 0;
    int i = blockIdx.x * 256 + threadIdx.x;
    if (i < NEDGE) atomicAdd(&cnt[getidx(ei, i64, NEDGE + i)], 1u);
}

// ---- edge update (round-4 proven version): e_new = LN(e + MLP([h_src|h_dst|e]))
__global__ __launch_bounds__(256) void edge_kernel(
    const ushort* __restrict__ hb, const void* __restrict__ e,
    const int* __restrict__ ei,
    const ushort* __restrict__ WT1, const void* __restrict__ be1,
    const ushort* __restrict__ WT2, const void* __restrict__ be2,
    const void* __restrict__ neg, const void* __restrict__ neb,
    void* __restrict__ out, const u32* __restrict__ flags)
{
    const bool f32 = flags[0] != 0, i64 = flags[1] != 0;
    constexpr int LDA = 72, LDB = 72, LDT = 136;
    __shared__ ushort Asm[64 * LDA];
    __shared__ ushort Bsm[128 * LDB];
    __shared__ ushort Tsm[64 * LDT];

    const int tid = threadIdx.x;
    const int wid = tid >> 6, lane = tid & 63;
    const int l16 = lane & 15, lg = lane >> 4;
    const int edge0 = blockIdx.x * 64;
    const int rm = wid * 16;

    f4 acc[8] = {};

    for (int kc = 0; kc < 10; ++kc) {
        const int k0 = kc * 64;
        __syncthreads();
        #pragma unroll
        for (int half = 0; half < 2; ++half) {
            int slot = tid + half * 256;
            int r = slot >> 3, c8 = (slot & 7) * 8;
            bf8 v;
            if (k0 < 256)      v = *(const bf8*)&hb[(size_t)getidx(ei, i64, edge0 + r) * HIDD + k0 + c8];
            else if (k0 < 512) v = *(const bf8*)&hb[(size_t)getidx(ei, i64, NEDGE + edge0 + r) * HIDD + k0 - 256 + c8];
            else               v = load8(e, (size_t)(edge0 + r) * ED + k0 - 512 + c8, f32);
            *(bf8*)&Asm[r * LDA + c8] = v;
        }
        #pragma unroll
        for (int it = 0; it < 4; ++it) {
            int slot = tid + it * 256;
            int n = slot >> 3, c8 = (slot & 7) * 8;
            *(bf8*)&Bsm[n * LDB + c8] = *(const bf8*)&WT1[(size_t)n * CAT + k0 + c8];
        }
        __syncthreads();
        #pragma unroll
        for (int ks = 0; ks < 2; ++ks) {
            bf8 a = *(const bf8*)&Asm[(rm + l16) * LDA + ks * 32 + lg * 8];
            #pragma unroll
            for (int f = 0; f < 8; ++f) {
                bf8 b = *(const bf8*)&Bsm[(f * 16 + l16) * LDB + ks * 32 + lg * 8];
                acc[f] = __builtin_amdgcn_mfma_f32_16x16x32_bf16(a, b, acc[f], 0, 0, 0);
            }
        }
    }

    #pragma unroll
    for (int f = 0; f < 8; ++f) {
        float bias = loadf(be1, f * 16 + l16, f32);
        #pragma unroll
        for (int r = 0; r < 4; ++r) {
            float v = acc[f][r] + bias;
            Tsm[(rm + lg * 4 + r) * LDT + f * 16 + l16] = f2bf(gelu_exact(v));
        }
    }

    f4 acc2[8] = {};
    for (int kc = 0; kc < 2; ++kc) {
        __syncthreads();
        #pragma unroll
        for (int it = 0; it < 4; ++it) {
            int slot = tid + it * 256;
            int n = slot >> 3, c8 = (slot & 7) * 8;
            *(bf8*)&Bsm[n * LDB + c8] = *(const bf8*)&WT2[(size_t)n * ED + kc * 64 + c8];
        }
        __syncthreads();
        #pragma unroll
        for (int ks = 0; ks < 2; ++ks) {
            bf8 a = *(const bf8*)&Tsm[(rm + l16) * LDT + kc * 64 + ks * 32 + lg * 8];
            #pragma unroll
            for (int f = 0; f < 8; ++f) {
                bf8 b = *(const bf8*)&Bsm[(f * 16 + l16) * LDB + ks * 32 + lg * 8];
                acc2[f] = __builtin_amdgcn_mfma_f32_16x16x32_bf16(a, b, acc2[f], 0, 0, 0);
            }
        }
    }

    __syncthreads();
    #pragma unroll
    for (int it = 0; it < 4; ++it) {
        int slot = tid + it * 256;
        int r = slot >> 4, c8 = (slot & 15) * 8;
        *(bf8*)&Bsm[r * LDT + c8] = load8(e, (size_t)(edge0 + r) * ED + c8, f32);
    }
    __syncthreads();

    float v[8][4];
    #pragma unroll
    for (int f = 0; f < 8; ++f) {
        float bias = loadf(be2, f * 16 + l16, f32);
        #pragma unroll
        for (int r = 0; r < 4; ++r) {
            int row = rm + lg * 4 + r;
            v[f][r] = acc2[f][r] + bias + bf2f(Bsm[row * LDT + f * 16 + l16]);
        }
    }
    #pragma unroll
    for (int r = 0; r < 4; ++r) {
        float s = 0.f;
        #pragma unroll
        for (int f = 0; f < 8; ++f) s += v[f][r];
        s += __shfl_xor(s, 1); s += __shfl_xor(s, 2);
        s += __shfl_xor(s, 4); s += __shfl_xor(s, 8);
        float mu = s * (1.0f / 128.0f);
        float q = 0.f;
        #pragma unroll
        for (int f = 0; f < 8; ++f) { float d = v[f][r] - mu; q += d * d; }
        q += __shfl_xor(q, 1); q += __shfl_xor(q, 2);
        q += __shfl_xor(q, 4); q += __shfl_xor(q, 8);
        float rstd = rsqrtf(q * (1.0f / 128.0f) + 1e-5f);
        int row = edge0 + rm + lg * 4 + r;
        #pragma unroll
        for (int f = 0; f < 8; ++f) {
            int col = f * 16 + l16;
            float y = (v[f][r] - mu) * rstd * loadf(neg, col, f32) + loadf(neb, col, f32);
            storef(out, (size_t)NNODE * HIDD + (size_t)row * ED + col, y, f32);
        }
    }
}

// ---- node phase 1: S[dst] += gelu([h_src|h_dst|e_new] @ Wv1 + bv1) ----
// 128 edges/block, 512 threads (8 waves, 2x4), wave tile 64x64.
// Per k-step: 4 A + 4 B ds_read_b128 feed 16 MFMAs.
__global__ __launch_bounds__(512) void node1_kernel(
    const ushort* __restrict__ hb, const void* __restrict__ out /*e_new*/,
    const int* __restrict__ ei,
    const ushort* __restrict__ WTv1, const void* __restrict__ bv1,
    float* __restrict__ S, const u32* __restrict__ flags)
{
    const bool f32 = flags[0] != 0, i64 = flags[1] != 0;
    constexpr int LDA = 72, LDB = 72;
    __shared__ ushort Asm[128 * LDA];   // [128 rows][64 k]
    __shared__ ushort Bsm[256 * LDB];   // n-major [256 n][64 k]

    const int tid = threadIdx.x;
    const int wid = tid >> 6, lane = tid & 63;
    const int l16 = lane & 15, lg = lane >> 4;
    const int wr = wid >> 2, wc = wid & 3;
    const int edge0 = blockIdx.x * 128;
    const size_t EOFF = (size_t)NNODE * HIDD;

    // staging: 2 fixed rows per thread across all kc
    size_t hsb[2], hdb[2], enb[2];
    int srow[2];
    #pragma unroll
    for (int it = 0; it < 2; ++it) {
        int r = it * 64 + (tid >> 3);
        srow[it] = r;
        hsb[it] = (size_t)getidx(ei, i64, edge0 + r) * HIDD;
        hdb[it] = (size_t)getidx(ei, i64, NEDGE + edge0 + r) * HIDD;
        enb[it] = EOFF + (size_t)(edge0 + r) * ED;
    }
    const int sc8 = (tid & 7) * 8;

    f4 acc[4][4] = {};

    for (int kc = 0; kc < 10; ++kc) {
        const int k0 = kc * 64;
        __syncthreads();
        #pragma unroll
        for (int it = 0; it < 2; ++it) {
            bf8 v;
            if (kc < 4)      v = *(const bf8*)&hb[hsb[it] + k0 + sc8];
            else if (kc < 8) v = *(const bf8*)&hb[hdb[it] + (k0 - 256) + sc8];
            else             v = load8(out, enb[it] + (k0 - 512) + sc8, f32);
            *(bf8*)&Asm[srow[it] * LDA + sc8] = v;
        }
        #pragma unroll
        for (int it = 0; it < 4; ++it) {
            int slot = tid + it * 512;
            int n = slot >> 3, cc = (slot & 7) * 8;
            *(bf8*)&Bsm[n * LDB + cc] = *(const bf8*)&WTv1[(size_t)n * CAT + k0 + cc];
        }
        __syncthreads();
        #pragma unroll
        for (int ks = 0; ks < 2; ++ks) {
            bf8 a[4], b[4];
            #pragma unroll
            for (int ai = 0; ai < 4; ++ai)
                a[ai] = *(const bf8*)&Asm[(wr * 64 + ai * 16 + l16) * LDA + ks * 32 + lg * 8];
            #pragma unroll
            for (int bi = 0; bi < 4; ++bi)
                b[bi] = *(const bf8*)&Bsm[(wc * 64 + bi * 16 + l16) * LDB + ks * 32 + lg * 8];
            #pragma unroll
            for (int ai = 0; ai < 4; ++ai)
                #pragma unroll
                for (int bi = 0; bi < 4; ++bi)
                    acc[ai][bi] = __builtin_amdgcn_mfma_f32_16x16x32_bf16(a[ai], b[bi], acc[ai][bi], 0, 0, 0);
        }
    }

    // gelu + scatter into S
    float bias[4];
    #pragma unroll
    for (int bi = 0; bi < 4; ++bi) bias[bi] = loadf(bv1, wc * 64 + bi * 16 + l16, f32);
    #pragma unroll
    for (int ai = 0; ai < 4; ++ai) {
        #pragma unroll
        for (int r = 0; r < 4; ++r) {
            int erow = edge0 + wr * 64 + ai * 16 + lg * 4 + r;
            int dst = getidx(ei, i64, NEDGE + erow);
            float* sp = S + (size_t)dst * HIDD + wc * 64;
            #pragma unroll
            for (int bi = 0; bi < 4; ++bi)
                atomicAdd(&sp[bi * 16 + l16], gelu_exact(acc[ai][bi][r] + bias[bi]));
        }
    }
}

// ---- node phase 2 + LN: h_new = LN(h + (S@Wv2 + cnt*bv2)/max(cnt,1)) ----
__global__ __launch_bounds__(256) void hn_gemm_kernel(
    const float* __restrict__ S, const ushort* __restrict__ WTv2,
    const void* __restrict__ bv2, const u32* __restrict__ cnt,
    const void* __restrict__ h,
    const void* __restrict__ nvg, const void* __restrict__ nvb,
    void* __restrict__ out, const u32* __restrict__ flags)
{
    const bool f32 = flags[0] != 0;
    constexpr int LDV = 260;
    __shared__ float Vsm[64 * LDV];

    const int tid = threadIdx.x;
    const int wid = tid >> 6, lane = tid & 63;
    const int l16 = lane & 15, lg = lane >> 4;
    const int node0 = blockIdx.x * 64;
    const int n0 = wid * 64;

    size_t ra[4];
    #pragma unroll
    for (int ai = 0; ai < 4; ++ai) {
        int row = node0 + ai * 16 + l16;
        ra[ai] = (size_t)(row < NNODE ? row : NNODE - 1) * HIDD;
    }
    int bb[4];
    #pragma unroll
    for (int bi = 0; bi < 4; ++bi) bb[bi] = (n0 + bi * 16 + l16) * HIDD;

    f4 acc[4][4] = {};
    for (int kc = 0; kc < 4; ++kc) {
        #pragma unroll
        for (int ks = 0; ks < 2; ++ks) {
            int kk = kc * 64 + ks * 32 + lg * 8;
            bf8 b[4];
            #pragma unroll
            for (int bi = 0; bi < 4; ++bi) b[bi] = *(const bf8*)&WTv2[bb[bi] + kk];
            #pragma unroll
            for (int ai = 0; ai < 4; ++ai) {
                bf8 a = load8(S, ra[ai] + kk, true);
                #pragma unroll
                for (int bi = 0; bi < 4; ++bi)
                    acc[ai][bi] = __builtin_amdgcn_mfma_f32_16x16x32_bf16(a, b[bi], acc[ai][bi], 0, 0, 0);
            }
        }
    }

    #pragma unroll
    for (int bi = 0; bi < 4; ++bi) {
        int col = n0 + bi * 16 + l16;
        float b2 = loadf(bv2, col, f32);
        #pragma unroll
        for (int ai = 0; ai < 4; ++ai)
            #pragma unroll
            for (int r = 0; r < 4; ++r) {
                int rowl = ai * 16 + lg * 4 + r;
                int gr = node0 + rowl;
                int grc = gr < NNODE ? gr : NNODE - 1;
                float c = (float)cnt[grc];
                float inv = 1.0f / fmaxf(c, 1.0f);
                float val = (acc[ai][bi][r] + c * b2) * inv
                          + loadf(h, (size_t)grc * HIDD + col, f32);
                Vsm[rowl * LDV + col] = val;
            }
    }
    __syncthreads();

    #pragma unroll
    for (int rr = 0; rr < 4; ++rr) {
        int rowl = wid * 16 + lg * 4 + rr;
        int gr = node0 + rowl;
        float x[16];
        #pragma unroll
        for (int f = 0; f < 16; ++f) x[f] = Vsm[rowl * LDV + f * 16 + l16];
        float s = 0.f;
        #pragma unroll
        for (int f = 0; f < 16; ++f) s += x[f];
        s += __shfl_xor(s, 1); s += __shfl_xor(s, 2);
        s += __shfl_xor(s, 4); s += __shfl_xor(s, 8);
        float mu = s * (1.0f / 256.0f);
        float q = 0.f;
        #pragma unroll
        for (int f = 0; f < 16; ++f) { float d = x[f] - mu; q += d * d; }
        q += __shfl_xor(q, 1); q += __shfl_xor(q, 2);
        q += __shfl_xor(q, 4); q += __shfl_xor(q, 8);
        float rstd = rsqrtf(q * (1.0f / 256.0f) + 1e-5f);
        if (gr < NNODE) {
            #pragma unroll
            for (int f = 0; f < 16; ++f) {
                int col = f * 16 + l16;
                float y = (x[f] - mu) * rstd * loadf(nvg, col, f32) + loadf(nvb, col, f32);
                storef(out, (size_t)gr * HIDD + col, y, f32);
            }
        }
    }
}

extern "C" void kernel_launch(void* const* d_in, const int* in_sizes, int n_in,
                              void* d_out, int out_size, void* d_ws, size_t ws_size,
                              hipStream_t stream)
{
    (void)in_sizes; (void)n_in; (void)out_size; (void)ws_size;
    const void* h   = d_in[0];
    const void* e   = d_in[1];
    const int*  ei  = (const int*)d_in[2];
    const void* We1 = d_in[3];
    const void* be1 = d_in[4];
    const void* We2 = d_in[5];
    const void* be2 = d_in[6];
    const void* Wv1 = d_in[7];
    const void* bv1 = d_in[8];
    const void* Wv2 = d_in[9];
    const void* bv2 = d_in[10];
    const void* neg = d_in[11];
    const void* neb = d_in[12];
    const void* nvg = d_in[13];
    const void* nvb = d_in[14];

    char* ws = (char*)d_ws;
    u32*   flags = (u32*)ws;                                    // 256B slot
    float* S     = (float*)(ws + 256);                          // 10.24 MB
    u32*   cnt   = (u32*)(ws + 256 + (size_t)NNODE * HIDD * 4); // 40 KB
    size_t off = 256 + (size_t)NNODE * HIDD * 4 + ((size_t)NNODE * 4 + 255) / 256 * 256;
    ushort* WT1  = (ushort*)(ws + off);            // [128][640]
    ushort* WT2  = WT1 + (size_t)ED * CAT;         // [128][128]
    ushort* WTv1 = WT2 + (size_t)ED * ED;          // [256][640]
    ushort* WTv2 = WTv1 + (size_t)HIDD * CAT;      // [256][256]
    ushort* hb   = WTv2 + (size_t)HIDD * HIDD;     // [10000][256] bf16

    hipMemsetAsync(S, 0, (size_t)NNODE * HIDD * 4 + (size_t)NNODE * 4, stream);
    detect_kernel<<<1, 64, 0, stream>>>((const u32*)h, (const u32*)ei, flags);

    wt_kernel<<<CAT,  ED,   0, stream>>>(We1, WT1, CAT, ED, flags);
    wt_kernel<<<ED,   ED,   0, stream>>>(We2, WT2, ED, ED, flags);
    wt_kernel<<<CAT,  HIDD, 0, stream>>>(Wv1, WTv1, CAT, HIDD, flags);
    wt_kernel<<<HIDD, HIDD, 0, stream>>>(Wv2, WTv2, HIDD, HIDD, flags);
    hconv_kernel<<<(NNODE * HIDD / 8 + 255) / 256, 256, 0, stream>>>(h, hb, flags);
    count_kernel<<<(NEDGE + 255) / 256, 256, 0, stream>>>(ei, cnt, flags);

    edge_kernel<<<NEDGE / 64, 256, 0, stream>>>(hb, e, ei, WT1, be1, WT2, be2,
                                                neg, neb, d_out, flags);
    node1_kernel<<<NEDGE / 128, 512, 0, stream>>>(hb, d_out, ei, WTv1, bv1, S, flags);
    hn_gemm_kernel<<<(NNODE + 63) / 64, 256, 0, stream>>>(S, WTv2, bv2, cnt, h,
                                                          nvg, nvb, d_out, flags);
}